// Round 5
// baseline (673.821 us; speedup 1.0000x reference)
//
#include <hip/hip_runtime.h>
#include <hip/hip_fp16.h>
#include <math.h>

#define Bb 64
#define Nn 1000
#define Gg 500
#define Hh 256
#define GP 512
#define NP 1024

// float offsets into d_ws (total 42,762,240 floats = 171 MB)
#define WS_MP   0u           // [B][H] fp32 column sums (zeroed each launch)
#define WS_QG   16384u       // [B][H] fp32 q_graph
#define WS_BM   32768u       // u16 [B][GP][64]  visited bitmask (4 MB)
#define WS_WCH  1081344u     // u16 [256][512] Wcat hi
#define WS_WCL  1146880u     // u16 [256][512] Wcat lo
#define WS_EH   1212416u     // u16 [B][N][H] emb hi
#define WS_EL   9404416u     // u16 [B][N][H] emb lo
#define WS_TH   17596416u    // u16 [B][H][NP] embT hi (dead after k_pool)
#define WS_TL   25985024u    // u16 [B][H][NP] embT lo
#define WS_PH   34373632u    // u16 [B][GP][H] pooled hi
#define WS_PL2  38567936u    // u16 [B][GP][H] pooled lo
#define WS_FH   WS_TH        // u16 [B][GP][H] fq hi (overlays embT)
#define WS_FL   WS_TL        // u16 [B][GP][H] fq lo

typedef __attribute__((ext_vector_type(8))) short bf16x8;
typedef __attribute__((ext_vector_type(8))) short short8;
typedef __attribute__((ext_vector_type(4))) float f32x4;
typedef __attribute__((ext_vector_type(4))) unsigned short u16x4;

#define MFMA(a,b,c) __builtin_amdgcn_mfma_f32_16x16x32_bf16(a,b,c,0,0,0)

__device__ __forceinline__ float tanh10(float s) {
  float a = fabsf(s);
  float e = __expf(-2.0f * a);
  float t = (1.0f - e) / (1.0f + e);
  return copysignf(10.0f * t, s);
}

__device__ __forceinline__ void split1(float v, unsigned short& hi, unsigned short& lo) {
  unsigned bits = __float_as_uint(v);
  hi = (unsigned short)(bits >> 16);
  float hf = __uint_as_float(bits & 0xFFFF0000u);
  lo = (unsigned short)(__float_as_uint(v - hf) >> 16);
}

// ---------------- zero mp: grid(64), block(256) ----------------
__global__ __launch_bounds__(256) void k_zero(float* __restrict__ ws) {
  ws[WS_MP + blockIdx.x * 256 + threadIdx.x] = 0.f;
}

// ---------------- prep: emb -> eh/el + th/tl + column sums ----------------
// grid(nt=16, ht=4, b=64), block(256)
__global__ __launch_bounds__(256) void k_prep(const float* __restrict__ emb,
                                              float* __restrict__ ws) {
  __shared__ float tile[64][65];
  __shared__ float csumL[256];
  int nt = blockIdx.x, ht = blockIdx.y, b = blockIdx.z;
  int t = threadIdx.x, c = t & 63, w = t >> 6;
  int n0 = nt * 64, h0 = ht * 64;
  unsigned short* eh = (unsigned short*)(ws + WS_EH);
  unsigned short* el = (unsigned short*)(ws + WS_EL);
  unsigned short* th = (unsigned short*)(ws + WS_TH);
  unsigned short* tl = (unsigned short*)(ws + WS_TL);
  float csum = 0.f;
#pragma unroll
  for (int rr = 0; rr < 16; ++rr) {
    int r = w * 16 + rr;
    int n = n0 + r;
    float v = 0.f;
    if (n < Nn) {
      size_t idx = ((size_t)(b * Nn + n)) * Hh + h0 + c;
      v = emb[idx];
      unsigned short hi, lo;
      split1(v, hi, lo);
      eh[idx] = hi; el[idx] = lo;
    }
    tile[r][c] = v;
    csum += v;
  }
  __syncthreads();
  {
    int h_l = t >> 2, nseg = t & 3;
    short8 h8a, h8b, l8a, l8b;
#pragma unroll
    for (int i = 0; i < 16; ++i) {
      float v = tile[nseg * 16 + i][h_l];
      unsigned short hi, lo;
      split1(v, hi, lo);
      if (i < 8) { h8a[i] = (short)hi; l8a[i] = (short)lo; }
      else       { h8b[i-8] = (short)hi; l8b[i-8] = (short)lo; }
    }
    size_t base = ((size_t)(b * Hh + h0 + h_l)) * NP + n0 + nseg * 16;
    *(short8*)(th + base) = h8a; *(short8*)(th + base + 8) = h8b;
    *(short8*)(tl + base) = l8a; *(short8*)(tl + base + 8) = l8b;
  }
  __syncthreads();
  csumL[t] = csum;
  __syncthreads();
  if (t < 64) {
    float s = csumL[t] + csumL[t+64] + csumL[t+128] + csumL[t+192];
    atomicAdd(ws + WS_MP + b * Hh + h0 + t, s);
  }
}

// ---------------- q_graph: grid(B), block(256) ----------------
__global__ __launch_bounds__(256) void k_qgraph(const float* __restrict__ Wg,
                                                float* __restrict__ ws) {
  __shared__ float mean[Hh];
  int b = blockIdx.x, t = threadIdx.x;
  mean[t] = ws[WS_MP + b*Hh + t] * (1.0f/Nn);
  __syncthreads();
  const float4* wrow = (const float4*)(Wg + (size_t)t * Hh);
  float acc = 0.f;
#pragma unroll
  for (int h4 = 0; h4 < Hh/4; ++h4) {
    float4 w = wrow[h4];
    acc += mean[h4*4]*w.x + mean[h4*4+1]*w.y + mean[h4*4+2]*w.z + mean[h4*4+3]*w.w;
  }
  ws[WS_QG + b*Hh + t] = acc;
}

// ---------------- Wcat bf16 hi/lo: grid(256), block(256) ----------------
__global__ __launch_bounds__(256) void k_wcat(const float* __restrict__ Wf,
                                              const float* __restrict__ Wl,
                                              const float* __restrict__ Wv,
                                              float* __restrict__ ws) {
  int o = blockIdx.x, k = threadIdx.x;
  unsigned short* wh = (unsigned short*)(ws + WS_WCH);
  unsigned short* wl = (unsigned short*)(ws + WS_WCL);
  unsigned short hi, lo;
  float v0 = Wv[o*Hh + k];
  split1(v0, hi, lo);
  wh[o*512 + k] = hi; wl[o*512 + k] = lo;
  float v1 = Wl[o*Hh + k] + Wf[o*Hh + k];
  split1(v1, hi, lo);
  wh[o*512 + 256 + k] = hi; wl[o*512 + 256 + k] = lo;
}

// ---------------- bitmask: gm -> 1 bit per (b,g,n): grid(B*GP/4), block(256) ----
__global__ __launch_bounds__(256) void k_bm(const float* __restrict__ gm,
                                            float* __restrict__ ws) {
  int w = threadIdx.x >> 6, l = threadIdx.x & 63;
  int row = blockIdx.x * 4 + w;          // b*GP + g
  int b = row >> 9, g = row & 511;
  unsigned long long* dst = (unsigned long long*)((unsigned short*)(ws + WS_BM) + (size_t)row * 64);
  if (g < Gg) {
    const float* src = gm + ((size_t)b * Gg + g) * Nn;
#pragma unroll
    for (int i = 0; i < 16; ++i) {
      int n = i * 64 + l;
      bool bit = (n < Nn) ? (src[n] < -1e30f) : false;
      unsigned long long m = __ballot(bit);
      if (l == i) dst[i] = m;
    }
  } else {
    if (l < 16) dst[l] = 0ull;
  }
}

// ---------------- pool MFMA: pooled[g][h] = (1/N) mask @ emb, bf16 hi/lo out ----
// grid(ht=2, gt=8, b=64), block(256); wave tile 64h x 32g
__global__ __launch_bounds__(256) void k_pool(float* __restrict__ ws) {
  int ht = blockIdx.x, gt = blockIdx.y, b = blockIdx.z;
  int t = threadIdx.x, w = t >> 6, lane = t & 63;
  int wr = w >> 1, wc = w & 1, l15 = lane & 15, lk = lane >> 4;
  const unsigned short* th = (const unsigned short*)(ws + WS_TH);
  const unsigned short* tl = (const unsigned short*)(ws + WS_TL);
  const unsigned short* bm = (const unsigned short*)(ws + WS_BM);
  unsigned short* ph = (unsigned short*)(ws + WS_PH);
  unsigned short* pl = (unsigned short*)(ws + WS_PL2);
  f32x4 acc[4][2] = {};
  int hbase = ht*128 + wr*64;
  int gbase = gt*64 + wc*32;
  size_t arow[4];
  const unsigned short* brow[2];
#pragma unroll
  for (int fm = 0; fm < 4; ++fm)
    arow[fm] = ((size_t)(b*Hh + hbase + fm*16 + l15)) * NP;
#pragma unroll
  for (int fn = 0; fn < 2; ++fn)
    brow[fn] = bm + ((size_t)(b*GP + gbase + fn*16 + l15)) * 64;
  int bitoff = (lk & 1) * 8;
  for (int k0 = 0; k0 < NP; k0 += 32) {
    bf16x8 ah[4], al[4], bmf[2];
#pragma unroll
    for (int fm = 0; fm < 4; ++fm) {
      ah[fm] = *(const bf16x8*)(th + arow[fm] + k0 + lk*8);
      al[fm] = *(const bf16x8*)(tl + arow[fm] + k0 + lk*8);
    }
#pragma unroll
    for (int fn = 0; fn < 2; ++fn) {
      unsigned c = brow[fn][(k0 >> 4) + (lk >> 1)];
#pragma unroll
      for (int i = 0; i < 8; ++i)
        bmf[fn][i] = ((c >> (bitoff + i)) & 1) ? (short)0x3F80 : (short)0;
    }
#pragma unroll
    for (int fm = 0; fm < 4; ++fm)
#pragma unroll
      for (int fn = 0; fn < 2; ++fn) {
        acc[fm][fn] = MFMA(ah[fm], bmf[fn], acc[fm][fn]);
        acc[fm][fn] = MFMA(al[fm], bmf[fn], acc[fm][fn]);
      }
  }
#pragma unroll
  for (int fm = 0; fm < 4; ++fm)
#pragma unroll
    for (int fn = 0; fn < 2; ++fn) {
      int g = gbase + fn*16 + l15;
      int h = hbase + fm*16 + lk*4;
      u16x4 vh, vl;
#pragma unroll
      for (int j = 0; j < 4; ++j) {
        unsigned short hi, lo;
        split1(acc[fm][fn][j] * (1.0f/Nn), hi, lo);
        vh[j] = hi; vl[j] = lo;
      }
      size_t idx = ((size_t)(b*GP + g)) * Hh + h;
      *(u16x4*)(ph + idx) = vh;
      *(u16x4*)(pl + idx) = vl;
    }
}

// ---------------- finalq MFMA (swapped): fq[g][o] = Wcat @ [pooled|emb[L]]^T + qg
// grid(ot=2, gt=8, b=64), block(256); wave tile 64o x 32g
__global__ __launch_bounds__(256) void k_finalq(const int* __restrict__ last_node,
                                                float* __restrict__ ws) {
  __shared__ int lL[64];
  int ot = blockIdx.x, gt = blockIdx.y, b = blockIdx.z;
  int t = threadIdx.x, w = t >> 6, lane = t & 63;
  int wr = w >> 1, wc = w & 1, l15 = lane & 15, lk = lane >> 4;
  const unsigned short* wch = (const unsigned short*)(ws + WS_WCH);
  const unsigned short* wcl = (const unsigned short*)(ws + WS_WCL);
  const unsigned short* ph = (const unsigned short*)(ws + WS_PH);
  const unsigned short* pl = (const unsigned short*)(ws + WS_PL2);
  const unsigned short* eh = (const unsigned short*)(ws + WS_EH);
  const unsigned short* el = (const unsigned short*)(ws + WS_EL);
  unsigned short* fh = (unsigned short*)(ws + WS_FH);
  unsigned short* fl = (unsigned short*)(ws + WS_FL);
  if (t < 64) {
    int g = gt*64 + t;
    lL[t] = last_node[b*Gg + (g < Gg ? g : Gg-1)];
  }
  __syncthreads();
  int obase = ot*128 + wr*64;
  int gbase = gt*64 + wc*32;
  f32x4 acc[4][2] = {};
  size_t arow[4], prow[2], lrow[2];
  int gidx[2];
#pragma unroll
  for (int fm = 0; fm < 4; ++fm)
    arow[fm] = ((size_t)(obase + fm*16 + l15)) * 512;
#pragma unroll
  for (int fn = 0; fn < 2; ++fn) {
    gidx[fn] = gbase + fn*16 + l15;
    prow[fn] = ((size_t)(b*GP + gidx[fn])) * Hh;
    lrow[fn] = ((size_t)(b*Nn + lL[wc*32 + fn*16 + l15])) * Hh;
  }
  for (int k0 = 0; k0 < 512; k0 += 32) {
    bf16x8 ahi[4], alo[4], bhi[2], blo[2];
#pragma unroll
    for (int fm = 0; fm < 4; ++fm) {
      ahi[fm] = *(const bf16x8*)(wch + arow[fm] + k0 + lk*8);
      alo[fm] = *(const bf16x8*)(wcl + arow[fm] + k0 + lk*8);
    }
    if (k0 < 256) {
#pragma unroll
      for (int fn = 0; fn < 2; ++fn) {
        bhi[fn] = *(const bf16x8*)(ph + prow[fn] + k0 + lk*8);
        blo[fn] = *(const bf16x8*)(pl + prow[fn] + k0 + lk*8);
      }
    } else {
#pragma unroll
      for (int fn = 0; fn < 2; ++fn) {
        bhi[fn] = *(const bf16x8*)(eh + lrow[fn] + (k0-256) + lk*8);
        blo[fn] = *(const bf16x8*)(el + lrow[fn] + (k0-256) + lk*8);
      }
    }
#pragma unroll
    for (int fm = 0; fm < 4; ++fm)
#pragma unroll
      for (int fn = 0; fn < 2; ++fn) {
        acc[fm][fn] = MFMA(ahi[fm], bhi[fn], acc[fm][fn]);
        acc[fm][fn] = MFMA(ahi[fm], blo[fn], acc[fm][fn]);
        acc[fm][fn] = MFMA(alo[fm], bhi[fn], acc[fm][fn]);
      }
  }
#pragma unroll
  for (int fm = 0; fm < 4; ++fm) {
    int o = obase + fm*16 + lk*4;
    float4 qv = *(const float4*)(ws + WS_QG + b*Hh + o);
    float q4[4] = {qv.x, qv.y, qv.z, qv.w};
#pragma unroll
    for (int fn = 0; fn < 2; ++fn) {
      u16x4 vh, vl;
#pragma unroll
      for (int j = 0; j < 4; ++j) {
        unsigned short hi, lo;
        split1(acc[fm][fn][j] + q4[j], hi, lo);
        vh[j] = hi; vl[j] = lo;
      }
      size_t idx = ((size_t)(b*GP + gidx[fn])) * Hh + o;
      *(u16x4*)(fh + idx) = vh;
      *(u16x4*)(fl + idx) = vl;
    }
  }
}

// ---------------- fused score + softmax + normalize ----------------
// grid(gt=16, b=64), block(512)=8 waves; block owns 32 g-rows x all n.
// wave: wn=w>>1 (n quarter), wg=w&1 (g half of 16); wave tile 32n x 16g.
#define PSTRIDE 1028
__global__ __launch_bounds__(512, 4) void k_score(const float* __restrict__ dists,
                                                  const int* __restrict__ last_node,
                                                  float* __restrict__ ws,
                                                  float* __restrict__ out) {
  __shared__ __align__(8) unsigned short pbuf[32 * PSTRIDE];  // 65792 B
  __shared__ int lL[32];
  __shared__ float rsp[8][16];
  __shared__ float inv[32];
  int gt = blockIdx.x, b = blockIdx.y;
  int t = threadIdx.x, w = t >> 6, lane = t & 63;
  int wn = w >> 1, wg = w & 1, l15 = lane & 15, lk = lane >> 4;
  const unsigned short* eh = (const unsigned short*)(ws + WS_EH);
  const unsigned short* el = (const unsigned short*)(ws + WS_EL);
  const unsigned short* fh = (const unsigned short*)(ws + WS_FH);
  const unsigned short* fl = (const unsigned short*)(ws + WS_FL);
  const unsigned short* bm = (const unsigned short*)(ws + WS_BM);
  if (t < 32) lL[t] = last_node[b*Gg + ((gt*32 + t) < Gg ? (gt*32 + t) : Gg-1)];
  __syncthreads();
  int g_local = wg*16 + l15;
  size_t frow = ((size_t)(b*GP + gt*32 + g_local)) * Hh;
  float rsum = 0.f;
  const float c2 = 0.70710678118654752f;
  for (int nt = 0; nt < 8; ++nt) {
    size_t arow[2];
#pragma unroll
    for (int fm = 0; fm < 2; ++fm) {
      int nr = nt*128 + wn*32 + fm*16 + l15;
      if (nr > Nn-1) nr = Nn-1;
      arow[fm] = ((size_t)(b*Nn + nr)) * Hh;
    }
    f32x4 acc[2] = {};
    for (int k0 = 0; k0 < 256; k0 += 32) {
      bf16x8 ahi[2], alo[2], bhi, blo;
#pragma unroll
      for (int fm = 0; fm < 2; ++fm) {
        ahi[fm] = *(const bf16x8*)(eh + arow[fm] + k0 + lk*8);
        alo[fm] = *(const bf16x8*)(el + arow[fm] + k0 + lk*8);
      }
      bhi = *(const bf16x8*)(fh + frow + k0 + lk*8);
      blo = *(const bf16x8*)(fl + frow + k0 + lk*8);
#pragma unroll
      for (int fm = 0; fm < 2; ++fm) {
        acc[fm] = MFMA(ahi[fm], bhi, acc[fm]);
        acc[fm] = MFMA(ahi[fm], blo, acc[fm]);
        acc[fm] = MFMA(alo[fm], bhi, acc[fm]);
      }
    }
    // epilogue: lane holds g = gt*32 + g_local, 4 consecutive n per fm
    int L = lL[g_local];
    unsigned gmrow = (unsigned)((size_t)0); // placate
#pragma unroll
    for (int fm = 0; fm < 2; ++fm) {
      int nb = nt*128 + wn*32 + fm*16 + lk*4;
      if (nb < Nn) {
        float4 d4 = *(const float4*)(dists + ((size_t)(b*Nn + L)) * Nn + nb);
        unsigned cbits = bm[((size_t)(b*GP + gt*32 + g_local)) * 64 + (nb >> 4)];
        int bo = nb & 15;
        float dd[4] = {d4.x, d4.y, d4.z, d4.w};
        float pv[4];
#pragma unroll
        for (int j = 0; j < 4; ++j) {
          float sc = acc[fm][j] * 0.0625f - dd[j] * c2;
          float p = ((cbits >> (bo + j)) & 1) ? 0.f : __expf(tanh10(sc) - 10.0f);
          pv[j] = p; rsum += p;
        }
        unsigned plo = (unsigned)__half_as_ushort(__float2half(pv[0])) |
                       ((unsigned)__half_as_ushort(__float2half(pv[1])) << 16);
        unsigned phi = (unsigned)__half_as_ushort(__float2half(pv[2])) |
                       ((unsigned)__half_as_ushort(__float2half(pv[3])) << 16);
        uint2 u = {plo, phi};
        *(uint2*)&pbuf[g_local * PSTRIDE + nb] = u;
      }
    }
  }
  // row-sum: reduce over lk within wave, then over wn across waves
  rsum += __shfl_xor(rsum, 16);
  rsum += __shfl_xor(rsum, 32);
  if (lk == 0) rsp[w][l15] = rsum;
  __syncthreads();
  if (t < 32) {
    int wgg = t >> 4, idx = t & 15;
    float s = rsp[0*2 + wgg][idx] + rsp[1*2 + wgg][idx] +
              rsp[2*2 + wgg][idx] + rsp[3*2 + wgg][idx];
    inv[t] = 1.0f / s;
  }
  __syncthreads();
  // normalize + store: 16 threads per g-row
  {
    int r = t >> 4, c0 = t & 15;
    int g = gt*32 + r;
    if (g < Gg) {
      float iv = inv[r];
      float* orow = out + ((size_t)(b*Gg + g)) * Nn;
      for (int f4 = c0; f4 < 250; f4 += 16) {
        uint2 u = *(const uint2*)&pbuf[r * PSTRIDE + f4*4];
        float4 o4;
        o4.x = __half2float(__ushort_as_half((unsigned short)(u.x & 0xFFFF))) * iv;
        o4.y = __half2float(__ushort_as_half((unsigned short)(u.x >> 16))) * iv;
        o4.z = __half2float(__ushort_as_half((unsigned short)(u.y & 0xFFFF))) * iv;
        o4.w = __half2float(__ushort_as_half((unsigned short)(u.y >> 16))) * iv;
        *(float4*)(orow + f4*4) = o4;
      }
    }
  }
}

extern "C" void kernel_launch(void* const* d_in, const int* in_sizes, int n_in,
                              void* d_out, int out_size, void* d_ws, size_t ws_size,
                              hipStream_t stream) {
  const float* emb       = (const float*)d_in[0];
  const float* dists     = (const float*)d_in[1];
  const int*   last_node = (const int*)d_in[2];
  const float* gm        = (const float*)d_in[3];
  const float* Wg        = (const float*)d_in[4];
  const float* Wf        = (const float*)d_in[5];
  const float* Wl        = (const float*)d_in[6];
  const float* Wv        = (const float*)d_in[7];
  float* out = (float*)d_out;
  float* ws  = (float*)d_ws;

  hipLaunchKernelGGL(k_zero,   dim3(64),        dim3(256), 0, stream, ws);
  hipLaunchKernelGGL(k_prep,   dim3(16,4,Bb),   dim3(256), 0, stream, emb, ws);
  hipLaunchKernelGGL(k_qgraph, dim3(Bb),        dim3(256), 0, stream, Wg, ws);
  hipLaunchKernelGGL(k_wcat,   dim3(256),       dim3(256), 0, stream, Wf, Wl, Wv, ws);
  hipLaunchKernelGGL(k_bm,     dim3(Bb*GP/4),   dim3(256), 0, stream, gm, ws);
  hipLaunchKernelGGL(k_pool,   dim3(2,8,Bb),    dim3(256), 0, stream, ws);
  hipLaunchKernelGGL(k_finalq, dim3(2,8,Bb),    dim3(256), 0, stream, last_node, ws);
  hipLaunchKernelGGL(k_score,  dim3(16,Bb),     dim3(512), 0, stream, dists, last_node, ws, out);
}

// Round 6
// 461.785 us; speedup vs baseline: 1.4592x; 1.4592x over previous
//
#include <hip/hip_runtime.h>
#include <hip/hip_fp16.h>
#include <math.h>

#define Bb 64
#define Nn 1000
#define Gg 500
#define Hh 256
#define GP 512
#define NP 1024

// float offsets into d_ws (total 42,762,240 floats = 171 MB, same as r5)
#define WS_MP   0u           // [B][H] fp32 column sums (zeroed each launch)
#define WS_QG   16384u       // [B][H] fp32 q_graph
#define WS_BM   32768u       // u16 [B][GP][64] visited bitmask
#define WS_WCH  1081344u     // u16 [256][512] Wcat hi
#define WS_WCL  1146880u     // u16 [256][512] Wcat lo
#define WS_EH   1212416u     // u16 [B][N][H] emb hi
#define WS_EL   9404416u     // u16 [B][N][H] emb lo
#define WS_TH   17596416u    // u16 [B][H][NP] embT hi (dead after k_pool)
#define WS_TL   25985024u    // u16 [B][H][NP] embT lo (dead after k_pool)
#define WS_PH   34373632u    // u16 [B][GP][H] pooled hi (dead after k_finalq)
#define WS_PL2  38567936u    // u16 [B][GP][H] pooled lo
#define WS_FH   17596416u    // u16 [B][GP][H] fq hi (overlays embT TH)
#define WS_FL   21790720u    // u16 [B][GP][H] fq lo (overlays embT TH 2nd half)
#define WS_PO   25985024u    // u16 [B][GP][1000] unnorm p (overlays TL+PH+PL2)
#define WS_RS   42369024u    // [B][GP] fp32 row sums (tail slack, zeroed)

typedef __attribute__((ext_vector_type(8))) short bf16x8;
typedef __attribute__((ext_vector_type(8))) short short8;
typedef __attribute__((ext_vector_type(4))) float f32x4;
typedef __attribute__((ext_vector_type(4))) unsigned short u16x4;

#define MFMA(a,b,c) __builtin_amdgcn_mfma_f32_16x16x32_bf16(a,b,c,0,0,0)
#define LROW 72   // LDS row stride in shorts (64 k + 8 pad = 144 B)

__device__ __forceinline__ float tanh10(float s) {
  float a = fabsf(s);
  float e = __expf(-2.0f * a);
  float t = (1.0f - e) / (1.0f + e);
  return copysignf(10.0f * t, s);
}

__device__ __forceinline__ void split1(float v, unsigned short& hi, unsigned short& lo) {
  unsigned bits = __float_as_uint(v);
  hi = (unsigned short)(bits >> 16);
  float hf = __uint_as_float(bits & 0xFFFF0000u);
  lo = (unsigned short)(__float_as_uint(v - hf) >> 16);
}

// ---------------- zero MP + RS: grid(192), block(256) ----------------
__global__ __launch_bounds__(256) void k_zero(float* __restrict__ ws) {
  int bid = blockIdx.x, t = threadIdx.x;
  if (bid < 64) ws[WS_MP + bid * 256 + t] = 0.f;
  else          ws[WS_RS + (bid - 64) * 256 + t] = 0.f;
}

// ---------------- prep: emb -> eh/el + th/tl + column sums ----------------
// grid(nt=16, ht=4, b=64), block(256)
__global__ __launch_bounds__(256) void k_prep(const float* __restrict__ emb,
                                              float* __restrict__ ws) {
  __shared__ float tile[64][65];
  __shared__ float csumL[256];
  int nt = blockIdx.x, ht = blockIdx.y, b = blockIdx.z;
  int t = threadIdx.x, c = t & 63, w = t >> 6;
  int n0 = nt * 64, h0 = ht * 64;
  unsigned short* eh = (unsigned short*)(ws + WS_EH);
  unsigned short* el = (unsigned short*)(ws + WS_EL);
  unsigned short* th = (unsigned short*)(ws + WS_TH);
  unsigned short* tl = (unsigned short*)(ws + WS_TL);
  float csum = 0.f;
#pragma unroll
  for (int rr = 0; rr < 16; ++rr) {
    int r = w * 16 + rr;
    int n = n0 + r;
    float v = 0.f;
    if (n < Nn) {
      size_t idx = ((size_t)(b * Nn + n)) * Hh + h0 + c;
      v = emb[idx];
      unsigned short hi, lo;
      split1(v, hi, lo);
      eh[idx] = hi; el[idx] = lo;
    }
    tile[r][c] = v;
    csum += v;
  }
  __syncthreads();
  {
    int h_l = t >> 2, nseg = t & 3;
    short8 h8a, h8b, l8a, l8b;
#pragma unroll
    for (int i = 0; i < 16; ++i) {
      float v = tile[nseg * 16 + i][h_l];
      unsigned short hi, lo;
      split1(v, hi, lo);
      if (i < 8) { h8a[i] = (short)hi; l8a[i] = (short)lo; }
      else       { h8b[i-8] = (short)hi; l8b[i-8] = (short)lo; }
    }
    size_t base = ((size_t)(b * Hh + h0 + h_l)) * NP + n0 + nseg * 16;
    *(short8*)(th + base) = h8a; *(short8*)(th + base + 8) = h8b;
    *(short8*)(tl + base) = l8a; *(short8*)(tl + base + 8) = l8b;
  }
  __syncthreads();
  csumL[t] = csum;
  __syncthreads();
  if (t < 64) {
    float s = csumL[t] + csumL[t+64] + csumL[t+128] + csumL[t+192];
    atomicAdd(ws + WS_MP + b * Hh + h0 + t, s);
  }
}

// ---------------- q_graph: grid(B), block(256) ----------------
__global__ __launch_bounds__(256) void k_qgraph(const float* __restrict__ Wg,
                                                float* __restrict__ ws) {
  __shared__ float mean[Hh];
  int b = blockIdx.x, t = threadIdx.x;
  mean[t] = ws[WS_MP + b*Hh + t] * (1.0f/Nn);
  __syncthreads();
  const float4* wrow = (const float4*)(Wg + (size_t)t * Hh);
  float acc = 0.f;
#pragma unroll
  for (int h4 = 0; h4 < Hh/4; ++h4) {
    float4 w = wrow[h4];
    acc += mean[h4*4]*w.x + mean[h4*4+1]*w.y + mean[h4*4+2]*w.z + mean[h4*4+3]*w.w;
  }
  ws[WS_QG + b*Hh + t] = acc;
}

// ---------------- Wcat bf16 hi/lo: grid(256), block(256) ----------------
__global__ __launch_bounds__(256) void k_wcat(const float* __restrict__ Wf,
                                              const float* __restrict__ Wl,
                                              const float* __restrict__ Wv,
                                              float* __restrict__ ws) {
  int o = blockIdx.x, k = threadIdx.x;
  unsigned short* wh = (unsigned short*)(ws + WS_WCH);
  unsigned short* wl = (unsigned short*)(ws + WS_WCL);
  unsigned short hi, lo;
  float v0 = Wv[o*Hh + k];
  split1(v0, hi, lo);
  wh[o*512 + k] = hi; wl[o*512 + k] = lo;
  float v1 = Wl[o*Hh + k] + Wf[o*Hh + k];
  split1(v1, hi, lo);
  wh[o*512 + 256 + k] = hi; wl[o*512 + 256 + k] = lo;
}

// ---------------- bitmask: gm -> 1 bit per (b,g,n): grid(B*GP/4), block(256) ----
__global__ __launch_bounds__(256) void k_bm(const float* __restrict__ gm,
                                            float* __restrict__ ws) {
  int w = threadIdx.x >> 6, l = threadIdx.x & 63;
  int row = blockIdx.x * 4 + w;          // b*GP + g
  int b = row >> 9, g = row & 511;
  unsigned long long* dst = (unsigned long long*)((unsigned short*)(ws + WS_BM) + (size_t)row * 64);
  if (g < Gg) {
    const float* src = gm + ((size_t)b * Gg + g) * Nn;
#pragma unroll
    for (int i = 0; i < 16; ++i) {
      int n = i * 64 + l;
      bool bit = (n < Nn) ? (src[n] < -1e30f) : false;
      unsigned long long m = __ballot(bit);
      if (l == i) dst[i] = m;
    }
  } else {
    if (l < 16) dst[l] = 0ull;
  }
}

// ---------------- pool GEMM (LDS-staged): pooled[g][h] = (1/N) mask @ emb ----
// grid(ht=4, gt=8, b=64), block(256)=2x2 waves, wave tile 32h x 32g, BK=64
__global__ __launch_bounds__(256, 4) void k_pool(float* __restrict__ ws) {
  __shared__ __align__(16) unsigned short sTH[64*LROW], sTL[64*LROW];
  int ht = blockIdx.x, gt = blockIdx.y, b = blockIdx.z;
  int t = threadIdx.x, w = t >> 6, lane = t & 63;
  int wh = w >> 1, wg = w & 1, l15 = lane & 15, lk = lane >> 4;
  const unsigned short* th = (const unsigned short*)(ws + WS_TH);
  const unsigned short* tl = (const unsigned short*)(ws + WS_TL);
  const unsigned short* bmp = (const unsigned short*)(ws + WS_BM);
  unsigned short* ph = (unsigned short*)(ws + WS_PH);
  unsigned short* pl = (unsigned short*)(ws + WS_PL2);
  int h0 = ht*64, g0 = gt*64;
  f32x4 acc[2][2] = {};
  const unsigned short* brow[2];
#pragma unroll
  for (int fn = 0; fn < 2; ++fn) {
    int g = g0 + wg*32 + fn*16 + l15; if (g > Gg-1) g = Gg-1;
    brow[fn] = bmp + ((size_t)(b*GP + g)) * 64;
  }
  int bitoff = (lk & 1) * 8;
  for (int st = 0; st < 16; ++st) {
    int k0 = st * 64;
    __syncthreads();
#pragma unroll
    for (int i = 0; i < 2; ++i) {
      int seg = t*2 + i, row = seg >> 3, s7 = seg & 7;
      size_t src = ((size_t)(b*Hh + h0 + row)) * NP + k0 + s7*8;
      *(bf16x8*)&sTH[row*LROW + s7*8] = *(const bf16x8*)(th + src);
      *(bf16x8*)&sTL[row*LROW + s7*8] = *(const bf16x8*)(tl + src);
    }
    __syncthreads();
#pragma unroll
    for (int kk = 0; kk < 64; kk += 32) {
      bf16x8 ah[2], al[2], bmf[2];
#pragma unroll
      for (int fm = 0; fm < 2; ++fm) {
        int r = (wh*32 + fm*16 + l15) * LROW + kk + lk*8;
        ah[fm] = *(const bf16x8*)&sTH[r];
        al[fm] = *(const bf16x8*)&sTL[r];
      }
#pragma unroll
      for (int fn = 0; fn < 2; ++fn) {
        unsigned c = brow[fn][((k0 + kk) >> 4) + (lk >> 1)];
#pragma unroll
        for (int i = 0; i < 8; ++i)
          bmf[fn][i] = ((c >> (bitoff + i)) & 1) ? (short)0x3F80 : (short)0;
      }
#pragma unroll
      for (int fm = 0; fm < 2; ++fm)
#pragma unroll
        for (int fn = 0; fn < 2; ++fn) {
          acc[fm][fn] = MFMA(ah[fm], bmf[fn], acc[fm][fn]);
          acc[fm][fn] = MFMA(al[fm], bmf[fn], acc[fm][fn]);
        }
    }
  }
#pragma unroll
  for (int fm = 0; fm < 2; ++fm)
#pragma unroll
    for (int fn = 0; fn < 2; ++fn) {
      int h = h0 + wh*32 + fm*16 + lk*4;
      int g = g0 + wg*32 + fn*16 + l15;
      u16x4 vh, vl;
#pragma unroll
      for (int j = 0; j < 4; ++j) {
        unsigned short hi, lo;
        split1(acc[fm][fn][j] * (1.0f/Nn), hi, lo);
        vh[j] = hi; vl[j] = lo;
      }
      size_t idx = ((size_t)(b*GP + g)) * Hh + h;
      *(u16x4*)(ph + idx) = vh;
      *(u16x4*)(pl + idx) = vl;
    }
}

// ---------------- finalq GEMM (LDS-staged): fq[g][o] = Wcat@[pooled|lastE]^T + qg
// grid(ot=4, gt=8, b=64), block(256)=2x2 waves, wave tile 32o x 32g, K=512, BK=64
__global__ __launch_bounds__(256, 4) void k_finalq(const int* __restrict__ last_node,
                                                   float* __restrict__ ws) {
  __shared__ __align__(16) unsigned short sAH[64*LROW], sAL[64*LROW],
                                          sBH[64*LROW], sBL[64*LROW];
  __shared__ int lL[64];
  int ot = blockIdx.x, gt = blockIdx.y, b = blockIdx.z;
  int t = threadIdx.x, w = t >> 6, lane = t & 63;
  int wo = w >> 1, wg = w & 1, l15 = lane & 15, lk = lane >> 4;
  const unsigned short* wch = (const unsigned short*)(ws + WS_WCH);
  const unsigned short* wcl = (const unsigned short*)(ws + WS_WCL);
  const unsigned short* ph = (const unsigned short*)(ws + WS_PH);
  const unsigned short* pl = (const unsigned short*)(ws + WS_PL2);
  const unsigned short* eh = (const unsigned short*)(ws + WS_EH);
  const unsigned short* el = (const unsigned short*)(ws + WS_EL);
  unsigned short* fh = (unsigned short*)(ws + WS_FH);
  unsigned short* fl = (unsigned short*)(ws + WS_FL);
  int o0 = ot*64, g0 = gt*64;
  if (t < 64) lL[t] = last_node[b*Gg + ((g0 + t) < Gg ? (g0 + t) : Gg-1)];
  f32x4 acc[2][2] = {};
  for (int st = 0; st < 8; ++st) {
    int k0 = st * 64;
    __syncthreads();
#pragma unroll
    for (int i = 0; i < 2; ++i) {
      int seg = t*2 + i, row = seg >> 3, s7 = seg & 7;
      size_t asrc = ((size_t)(o0 + row)) * 512 + k0 + s7*8;
      *(bf16x8*)&sAH[row*LROW + s7*8] = *(const bf16x8*)(wch + asrc);
      *(bf16x8*)&sAL[row*LROW + s7*8] = *(const bf16x8*)(wcl + asrc);
      if (k0 < 256) {
        size_t bsrc = ((size_t)(b*GP + g0 + row)) * Hh + k0 + s7*8;
        *(bf16x8*)&sBH[row*LROW + s7*8] = *(const bf16x8*)(ph + bsrc);
        *(bf16x8*)&sBL[row*LROW + s7*8] = *(const bf16x8*)(pl + bsrc);
      } else {
        size_t bsrc = ((size_t)(b*Nn + lL[row])) * Hh + (k0 - 256) + s7*8;
        *(bf16x8*)&sBH[row*LROW + s7*8] = *(const bf16x8*)(eh + bsrc);
        *(bf16x8*)&sBL[row*LROW + s7*8] = *(const bf16x8*)(el + bsrc);
      }
    }
    __syncthreads();
#pragma unroll
    for (int kk = 0; kk < 64; kk += 32) {
      bf16x8 ahi[2], alo[2], bhi[2], blo[2];
#pragma unroll
      for (int fm = 0; fm < 2; ++fm) {
        int r = (wo*32 + fm*16 + l15) * LROW + kk + lk*8;
        ahi[fm] = *(const bf16x8*)&sAH[r];
        alo[fm] = *(const bf16x8*)&sAL[r];
      }
#pragma unroll
      for (int fn = 0; fn < 2; ++fn) {
        int r = (wg*32 + fn*16 + l15) * LROW + kk + lk*8;
        bhi[fn] = *(const bf16x8*)&sBH[r];
        blo[fn] = *(const bf16x8*)&sBL[r];
      }
#pragma unroll
      for (int fm = 0; fm < 2; ++fm)
#pragma unroll
        for (int fn = 0; fn < 2; ++fn) {
          acc[fm][fn] = MFMA(ahi[fm], bhi[fn], acc[fm][fn]);
          acc[fm][fn] = MFMA(ahi[fm], blo[fn], acc[fm][fn]);
          acc[fm][fn] = MFMA(alo[fm], bhi[fn], acc[fm][fn]);
        }
    }
  }
#pragma unroll
  for (int fm = 0; fm < 2; ++fm) {
    int o = o0 + wo*32 + fm*16 + lk*4;
    float4 qv = *(const float4*)(ws + WS_QG + b*Hh + o);
    float q4[4] = {qv.x, qv.y, qv.z, qv.w};
#pragma unroll
    for (int fn = 0; fn < 2; ++fn) {
      int g = g0 + wg*32 + fn*16 + l15;
      u16x4 vh, vl;
#pragma unroll
      for (int j = 0; j < 4; ++j) {
        unsigned short hi, lo;
        split1(acc[fm][fn][j] + q4[j], hi, lo);
        vh[j] = hi; vl[j] = lo;
      }
      size_t idx = ((size_t)(b*GP + g)) * Hh + o;
      *(u16x4*)(fh + idx) = vh;
      *(u16x4*)(fl + idx) = vl;
    }
  }
}

// ---------------- score GEMM (LDS-staged) + fp16 p + rowsum atomics ----------
// grid(nt=16, gt=8, b=64), block(256)=2x2 waves, wave tile 32n x 32g, K=256, BK=64
__global__ __launch_bounds__(256, 4) void k_score(const float* __restrict__ dists,
                                                  const int* __restrict__ last_node,
                                                  float* __restrict__ ws) {
  __shared__ __align__(16) unsigned short sEH[64*LROW], sEL[64*LROW],
                                          sFH[64*LROW], sFL[64*LROW];
  __shared__ int lL[64];
  int nt = blockIdx.x, gt = blockIdx.y, b = blockIdx.z;
  int t = threadIdx.x, w = t >> 6, lane = t & 63;
  int wn = w >> 1, wg = w & 1, l15 = lane & 15, lk = lane >> 4;
  const unsigned short* eh = (const unsigned short*)(ws + WS_EH);
  const unsigned short* el = (const unsigned short*)(ws + WS_EL);
  const unsigned short* fh = (const unsigned short*)(ws + WS_FH);
  const unsigned short* fl = (const unsigned short*)(ws + WS_FL);
  const unsigned short* bmp = (const unsigned short*)(ws + WS_BM);
  unsigned short* po = (unsigned short*)(ws + WS_PO);
  float* rs = ws + WS_RS;
  int n0 = nt*64, g0 = gt*64;
  if (t < 64) lL[t] = last_node[b*Gg + ((g0 + t) < Gg ? (g0 + t) : Gg-1)];
  f32x4 acc[2][2] = {};
  for (int st = 0; st < 4; ++st) {
    int k0 = st * 64;
    __syncthreads();
#pragma unroll
    for (int i = 0; i < 2; ++i) {
      int seg = t*2 + i, row = seg >> 3, s7 = seg & 7;
      int n = n0 + row; if (n > Nn-1) n = Nn-1;
      size_t esrc = ((size_t)(b*Nn + n)) * Hh + k0 + s7*8;
      *(bf16x8*)&sEH[row*LROW + s7*8] = *(const bf16x8*)(eh + esrc);
      *(bf16x8*)&sEL[row*LROW + s7*8] = *(const bf16x8*)(el + esrc);
      size_t fsrc = ((size_t)(b*GP + g0 + row)) * Hh + k0 + s7*8;
      *(bf16x8*)&sFH[row*LROW + s7*8] = *(const bf16x8*)(fh + fsrc);
      *(bf16x8*)&sFL[row*LROW + s7*8] = *(const bf16x8*)(fl + fsrc);
    }
    __syncthreads();
#pragma unroll
    for (int kk = 0; kk < 64; kk += 32) {
      bf16x8 ahi[2], alo[2], bhi[2], blo[2];
#pragma unroll
      for (int fm = 0; fm < 2; ++fm) {
        int r = (wn*32 + fm*16 + l15) * LROW + kk + lk*8;
        ahi[fm] = *(const bf16x8*)&sEH[r];
        alo[fm] = *(const bf16x8*)&sEL[r];
      }
#pragma unroll
      for (int fn = 0; fn < 2; ++fn) {
        int r = (wg*32 + fn*16 + l15) * LROW + kk + lk*8;
        bhi[fn] = *(const bf16x8*)&sFH[r];
        blo[fn] = *(const bf16x8*)&sFL[r];
      }
#pragma unroll
      for (int fm = 0; fm < 2; ++fm)
#pragma unroll
        for (int fn = 0; fn < 2; ++fn) {
          acc[fm][fn] = MFMA(ahi[fm], bhi[fn], acc[fm][fn]);
          acc[fm][fn] = MFMA(ahi[fm], blo[fn], acc[fm][fn]);
          acc[fm][fn] = MFMA(alo[fm], bhi[fn], acc[fm][fn]);
        }
    }
  }
  const float c2 = 0.70710678118654752f;
#pragma unroll
  for (int fn = 0; fn < 2; ++fn) {
    int gl = wg*32 + fn*16 + l15;
    int g = g0 + gl;
    if (g < Gg) {
      int L = lL[gl];
      const float* drow = dists + ((size_t)(b*Nn + L)) * Nn;
      const unsigned short* bmr = bmp + ((size_t)(b*GP + g)) * 64;
      unsigned short* prow = po + (size_t)(b*GP + g) * 1000;
      float s = 0.f;
#pragma unroll
      for (int fm = 0; fm < 2; ++fm) {
        int n = n0 + wn*32 + fm*16 + lk*4;
        if (n < Nn) {
          float4 d4 = *(const float4*)(drow + n);
          unsigned cb = bmr[n >> 4];
          int bo = n & 15;
          float dd[4] = {d4.x, d4.y, d4.z, d4.w};
          unsigned short h4[4];
#pragma unroll
          for (int j = 0; j < 4; ++j) {
            float sc = acc[fm][fn][j] * 0.0625f - dd[j] * c2;
            float p = ((cb >> (bo + j)) & 1) ? 0.f : __expf(tanh10(sc) - 10.0f);
            s += p;
            h4[j] = __half_as_ushort(__float2half(p));
          }
          uint2 u = { (unsigned)h4[0] | ((unsigned)h4[1] << 16),
                      (unsigned)h4[2] | ((unsigned)h4[3] << 16) };
          *(uint2*)(prow + n) = u;
        }
      }
      s += __shfl_xor(s, 16);
      s += __shfl_xor(s, 32);
      if (lk == 0) atomicAdd(rs + b*GP + g, s);
    }
  }
}

// ---------------- normalize: out[g][n] = fp16 p * (1/rs): grid(31250) ---------
__global__ __launch_bounds__(256) void k_norm(const float* __restrict__ ws,
                                              float* __restrict__ out) {
  int idx = blockIdx.x * 256 + threadIdx.x;   // float4 index, < 8,000,000
  int bg = idx / 250;                         // b*Gg + g
  int n = (idx - bg * 250) * 4;
  int b = bg / Gg, g = bg - b * Gg;
  const unsigned short* po = (const unsigned short*)(ws + WS_PO);
  float inv = 1.0f / ws[WS_RS + b*GP + g];
  uint2 u = *(const uint2*)(po + (size_t)(b*GP + g) * 1000 + n);
  float4 o4;
  o4.x = __half2float(__ushort_as_half((unsigned short)(u.x & 0xFFFF))) * inv;
  o4.y = __half2float(__ushort_as_half((unsigned short)(u.x >> 16))) * inv;
  o4.z = __half2float(__ushort_as_half((unsigned short)(u.y & 0xFFFF))) * inv;
  o4.w = __half2float(__ushort_as_half((unsigned short)(u.y >> 16))) * inv;
  *(float4*)(out + (size_t)bg * Nn + n) = o4;
}

extern "C" void kernel_launch(void* const* d_in, const int* in_sizes, int n_in,
                              void* d_out, int out_size, void* d_ws, size_t ws_size,
                              hipStream_t stream) {
  const float* emb       = (const float*)d_in[0];
  const float* dists     = (const float*)d_in[1];
  const int*   last_node = (const int*)d_in[2];
  const float* gm        = (const float*)d_in[3];
  const float* Wg        = (const float*)d_in[4];
  const float* Wf        = (const float*)d_in[5];
  const float* Wl        = (const float*)d_in[6];
  const float* Wv        = (const float*)d_in[7];
  float* out = (float*)d_out;
  float* ws  = (float*)d_ws;

  hipLaunchKernelGGL(k_zero,   dim3(192),       dim3(256), 0, stream, ws);
  hipLaunchKernelGGL(k_prep,   dim3(16,4,Bb),   dim3(256), 0, stream, emb, ws);
  hipLaunchKernelGGL(k_qgraph, dim3(Bb),        dim3(256), 0, stream, Wg, ws);
  hipLaunchKernelGGL(k_wcat,   dim3(256),       dim3(256), 0, stream, Wf, Wl, Wv, ws);
  hipLaunchKernelGGL(k_bm,     dim3(Bb*GP/4),   dim3(256), 0, stream, gm, ws);
  hipLaunchKernelGGL(k_pool,   dim3(4,8,Bb),    dim3(256), 0, stream, ws);
  hipLaunchKernelGGL(k_finalq, dim3(4,8,Bb),    dim3(256), 0, stream, last_node, ws);
  hipLaunchKernelGGL(k_score,  dim3(16,8,Bb),   dim3(256), 0, stream, dists, last_node, ws);
  hipLaunchKernelGGL(k_norm,   dim3(31250),     dim3(256), 0, stream, ws, out);
}

// Round 7
// 417.001 us; speedup vs baseline: 1.6159x; 1.1074x over previous
//
#include <hip/hip_runtime.h>
#include <hip/hip_fp16.h>
#include <math.h>

#define Bb 64
#define Nn 1000
#define Gg 500
#define Hh 256
#define GP 512
#define NP 1024

// float offsets into d_ws (total ~170 MB)
#define WS_MP   0u           // [B][H] fp32 column sums (zeroed each launch)
#define WS_QG   16384u       // [B][H] fp32 q_graph
#define WS_BM   32768u       // u16 [B][GP][64] visited bitmask
#define WS_WCH  1081344u     // u16 [256][512] Wcat hi
#define WS_WCL  1146880u     // u16 [256][512] Wcat lo
#define WS_EH   1212416u     // u16 [B][N][H] emb hi
#define WS_EL   9404416u     // u16 [B][N][H] emb lo
#define WS_TH   17596416u    // u16 [B][H][NP] embT hi (dead after k_pool)
#define WS_TL   25985024u    // u16 [B][H][NP] embT lo (dead after k_pool)
#define WS_PH   34373632u    // u16 [B][GP][H] pooled hi (dead after k_finalq)
#define WS_PL2  38567936u    // u16 [B][GP][H] pooled lo
#define WS_FH   17596416u    // u16 [B][GP][H] fq hi (overlays embT TH)
#define WS_FL   21790720u    // u16 [B][GP][H] fq lo (overlays TH 2nd half)
#define WS_PO   25985024u    // u16 [B][GP][1000] unnorm p (overlays TL+PH+PL2)
#define WS_RS   42369024u    // [B][GP] fp32 row sums (zeroed)

typedef __attribute__((ext_vector_type(8))) short bf16x8;
typedef __attribute__((ext_vector_type(8))) short short8;
typedef __attribute__((ext_vector_type(4))) float f32x4;
typedef __attribute__((ext_vector_type(4))) unsigned short u16x4;

#define MFMA(a,b,c) __builtin_amdgcn_mfma_f32_16x16x32_bf16(a,b,c,0,0,0)
// swizzled LDS offset (shorts): 64-short rows, 8 chunks of 8 bf16 (16B)
#define SW(row, chunk) (((row) << 6) + ((((chunk) ^ ((row) & 7))) << 3))

__device__ __forceinline__ float tanh10(float s) {
  float a = fabsf(s);
  float e = __expf(-2.0f * a);
  float t = (1.0f - e) / (1.0f + e);
  return copysignf(10.0f * t, s);
}

__device__ __forceinline__ void split1(float v, unsigned short& hi, unsigned short& lo) {
  unsigned bits = __float_as_uint(v);
  hi = (unsigned short)(bits >> 16);
  float hf = __uint_as_float(bits & 0xFFFF0000u);
  lo = (unsigned short)(__float_as_uint(v - hf) >> 16);
}

// ---------------- zero MP + RS: grid(192), block(256) ----------------
__global__ __launch_bounds__(256) void k_zero(float* __restrict__ ws) {
  int bid = blockIdx.x, t = threadIdx.x;
  if (bid < 64) ws[WS_MP + bid * 256 + t] = 0.f;
  else          ws[WS_RS + (bid - 64) * 256 + t] = 0.f;
}

// ---------------- prep: emb -> eh/el + th/tl + column sums ----------------
// grid(nt=16, ht=4, b=64), block(256)
__global__ __launch_bounds__(256) void k_prep(const float* __restrict__ emb,
                                              float* __restrict__ ws) {
  __shared__ float tile[64][65];
  __shared__ float csumL[256];
  int nt = blockIdx.x, ht = blockIdx.y, b = blockIdx.z;
  int t = threadIdx.x, c = t & 63, w = t >> 6;
  int n0 = nt * 64, h0 = ht * 64;
  unsigned short* eh = (unsigned short*)(ws + WS_EH);
  unsigned short* el = (unsigned short*)(ws + WS_EL);
  unsigned short* th = (unsigned short*)(ws + WS_TH);
  unsigned short* tl = (unsigned short*)(ws + WS_TL);
  float csum = 0.f;
#pragma unroll
  for (int rr = 0; rr < 16; ++rr) {
    int r = w * 16 + rr;
    int n = n0 + r;
    float v = 0.f;
    if (n < Nn) {
      size_t idx = ((size_t)(b * Nn + n)) * Hh + h0 + c;
      v = emb[idx];
      unsigned short hi, lo;
      split1(v, hi, lo);
      eh[idx] = hi; el[idx] = lo;
    }
    tile[r][c] = v;
    csum += v;
  }
  __syncthreads();
  {
    int h_l = t >> 2, nseg = t & 3;
    short8 h8a, h8b, l8a, l8b;
#pragma unroll
    for (int i = 0; i < 16; ++i) {
      float v = tile[nseg * 16 + i][h_l];
      unsigned short hi, lo;
      split1(v, hi, lo);
      if (i < 8) { h8a[i] = (short)hi; l8a[i] = (short)lo; }
      else       { h8b[i-8] = (short)hi; l8b[i-8] = (short)lo; }
    }
    size_t base = ((size_t)(b * Hh + h0 + h_l)) * NP + n0 + nseg * 16;
    *(short8*)(th + base) = h8a; *(short8*)(th + base + 8) = h8b;
    *(short8*)(tl + base) = l8a; *(short8*)(tl + base + 8) = l8b;
  }
  __syncthreads();
  csumL[t] = csum;
  __syncthreads();
  if (t < 64) {
    float s = csumL[t] + csumL[t+64] + csumL[t+128] + csumL[t+192];
    atomicAdd(ws + WS_MP + b * Hh + h0 + t, s);
  }
}

// ---------------- q_graph: grid(B), block(256) ----------------
__global__ __launch_bounds__(256) void k_qgraph(const float* __restrict__ Wg,
                                                float* __restrict__ ws) {
  __shared__ float mean[Hh];
  int b = blockIdx.x, t = threadIdx.x;
  mean[t] = ws[WS_MP + b*Hh + t] * (1.0f/Nn);
  __syncthreads();
  const float4* wrow = (const float4*)(Wg + (size_t)t * Hh);
  float acc = 0.f;
#pragma unroll
  for (int h4 = 0; h4 < Hh/4; ++h4) {
    float4 w = wrow[h4];
    acc += mean[h4*4]*w.x + mean[h4*4+1]*w.y + mean[h4*4+2]*w.z + mean[h4*4+3]*w.w;
  }
  ws[WS_QG + b*Hh + t] = acc;
}

// ---------------- Wcat bf16 hi/lo: grid(256), block(256) ----------------
__global__ __launch_bounds__(256) void k_wcat(const float* __restrict__ Wf,
                                              const float* __restrict__ Wl,
                                              const float* __restrict__ Wv,
                                              float* __restrict__ ws) {
  int o = blockIdx.x, k = threadIdx.x;
  unsigned short* wh = (unsigned short*)(ws + WS_WCH);
  unsigned short* wl = (unsigned short*)(ws + WS_WCL);
  unsigned short hi, lo;
  float v0 = Wv[o*Hh + k];
  split1(v0, hi, lo);
  wh[o*512 + k] = hi; wl[o*512 + k] = lo;
  float v1 = Wl[o*Hh + k] + Wf[o*Hh + k];
  split1(v1, hi, lo);
  wh[o*512 + 256 + k] = hi; wl[o*512 + 256 + k] = lo;
}

// ---------------- bitmask: gm -> 1 bit per (b,g,n): grid(B*GP/4), block(256) ----
__global__ __launch_bounds__(256) void k_bm(const float* __restrict__ gm,
                                            float* __restrict__ ws) {
  int w = threadIdx.x >> 6, l = threadIdx.x & 63;
  int row = blockIdx.x * 4 + w;          // b*GP + g
  int b = row >> 9, g = row & 511;
  unsigned long long* dst = (unsigned long long*)((unsigned short*)(ws + WS_BM) + (size_t)row * 64);
  if (g < Gg) {
    const float* src = gm + ((size_t)b * Gg + g) * Nn;
#pragma unroll
    for (int i = 0; i < 16; ++i) {
      int n = i * 64 + l;
      bool bit = (n < Nn) ? (src[n] < -1e30f) : false;
      unsigned long long m = __ballot(bit);
      if (l == i) dst[i] = m;
    }
  } else {
    if (l < 16) dst[l] = 0ull;
  }
}

// ---------------- pool GEMM: pooled[g][h] = (1/N) mask @ emb ----------------
// grid(ht=2, gt=4, b=64), block(512)=8 waves (2 wh x 4 wg), wave 64h x 32g, BK=64
__global__ __launch_bounds__(512, 2) void k_pool(float* __restrict__ ws) {
  __shared__ __align__(16) unsigned short sTH[128*64], sTL[128*64];
  int ht = blockIdx.x, gt = blockIdx.y, b = blockIdx.z;
  int t = threadIdx.x, w = t >> 6, lane = t & 63;
  int wh = w >> 2, wg = w & 3, l15 = lane & 15, lk = lane >> 4;
  const unsigned short* th = (const unsigned short*)(ws + WS_TH);
  const unsigned short* tl = (const unsigned short*)(ws + WS_TL);
  const unsigned short* bmp = (const unsigned short*)(ws + WS_BM);
  unsigned short* ph = (unsigned short*)(ws + WS_PH);
  unsigned short* pl = (unsigned short*)(ws + WS_PL2);
  int h0 = ht*128, g0 = gt*128;
  f32x4 acc[4][2] = {};
  const unsigned short* brow[2];
#pragma unroll
  for (int fn = 0; fn < 2; ++fn)
    brow[fn] = bmp + ((size_t)(b*GP + g0 + wg*32 + fn*16 + l15)) * 64;
  int bitoff = (lk & 1) * 8;
  int srow = t >> 2, scb = t & 3;
  size_t sbase = ((size_t)(b*Hh + h0 + srow)) * NP;
  for (int st = 0; st < 16; ++st) {
    int k0 = st * 64;
#pragma unroll
    for (int i = 0; i < 2; ++i) {
      int cc = scb + i*4;
      int d = SW(srow, cc);
      *(bf16x8*)&sTH[d] = *(const bf16x8*)(th + sbase + k0 + cc*8);
      *(bf16x8*)&sTL[d] = *(const bf16x8*)(tl + sbase + k0 + cc*8);
    }
    __syncthreads();
#pragma unroll
    for (int kk = 0; kk < 64; kk += 32) {
      bf16x8 ah[4], al[4], bmf[2];
#pragma unroll
      for (int fm = 0; fm < 4; ++fm) {
        int ar = wh*64 + fm*16 + l15;
        int d = SW(ar, (kk>>3) + lk);
        ah[fm] = *(const bf16x8*)&sTH[d];
        al[fm] = *(const bf16x8*)&sTL[d];
      }
#pragma unroll
      for (int fn = 0; fn < 2; ++fn) {
        unsigned c = brow[fn][((k0 + kk) >> 4) + (lk >> 1)];
#pragma unroll
        for (int i = 0; i < 8; ++i)
          bmf[fn][i] = ((c >> (bitoff + i)) & 1) ? (short)0x3F80 : (short)0;
      }
#pragma unroll
      for (int fm = 0; fm < 4; ++fm)
#pragma unroll
        for (int fn = 0; fn < 2; ++fn) {
          acc[fm][fn] = MFMA(ah[fm], bmf[fn], acc[fm][fn]);
          acc[fm][fn] = MFMA(al[fm], bmf[fn], acc[fm][fn]);
        }
    }
    __syncthreads();
  }
#pragma unroll
  for (int fm = 0; fm < 4; ++fm)
#pragma unroll
    for (int fn = 0; fn < 2; ++fn) {
      int h = h0 + wh*64 + fm*16 + lk*4;
      int g = g0 + wg*32 + fn*16 + l15;
      u16x4 vh, vl;
#pragma unroll
      for (int j = 0; j < 4; ++j) {
        unsigned short hi, lo;
        split1(acc[fm][fn][j] * (1.0f/Nn), hi, lo);
        vh[j] = hi; vl[j] = lo;
      }
      size_t idx = ((size_t)(b*GP + g)) * Hh + h;
      *(u16x4*)(ph + idx) = vh;
      *(u16x4*)(pl + idx) = vl;
    }
}

// ---------------- finalq GEMM: fq[g][o] = Wcat@[pooled|lastE]^T + qg ----------
// grid(ot=2, gt=4, b=64), block(512)=8 waves (2 wo x 4 wg), wave 64o x 32g, K=512
__global__ __launch_bounds__(512, 2) void k_finalq(const int* __restrict__ last_node,
                                                   float* __restrict__ ws) {
  __shared__ __align__(16) unsigned short sAH[128*64], sAL[128*64],
                                          sBH[128*64], sBL[128*64];
  __shared__ int lL[128];
  int ot = blockIdx.x, gt = blockIdx.y, b = blockIdx.z;
  int t = threadIdx.x, w = t >> 6, lane = t & 63;
  int wo = w >> 2, wg = w & 3, l15 = lane & 15, lk = lane >> 4;
  const unsigned short* wch = (const unsigned short*)(ws + WS_WCH);
  const unsigned short* wcl = (const unsigned short*)(ws + WS_WCL);
  const unsigned short* ph = (const unsigned short*)(ws + WS_PH);
  const unsigned short* pl = (const unsigned short*)(ws + WS_PL2);
  const unsigned short* eh = (const unsigned short*)(ws + WS_EH);
  const unsigned short* el = (const unsigned short*)(ws + WS_EL);
  unsigned short* fh = (unsigned short*)(ws + WS_FH);
  unsigned short* fl = (unsigned short*)(ws + WS_FL);
  int o0 = ot*128, g0 = gt*128;
  if (t < 128) lL[t] = last_node[b*Gg + ((g0 + t) < Gg ? (g0 + t) : Gg-1)];
  __syncthreads();
  f32x4 acc[4][2] = {};
  int srow = t >> 2, scb = t & 3;
  size_t abase = ((size_t)(o0 + srow)) * 512;
  int Lrow = lL[srow];
  for (int st = 0; st < 8; ++st) {
    int k0 = st * 64;
#pragma unroll
    for (int i = 0; i < 2; ++i) {
      int cc = scb + i*4;
      int d = SW(srow, cc);
      *(bf16x8*)&sAH[d] = *(const bf16x8*)(wch + abase + k0 + cc*8);
      *(bf16x8*)&sAL[d] = *(const bf16x8*)(wcl + abase + k0 + cc*8);
      if (k0 < 256) {
        size_t bsrc = ((size_t)(b*GP + g0 + srow)) * Hh + k0 + cc*8;
        *(bf16x8*)&sBH[d] = *(const bf16x8*)(ph + bsrc);
        *(bf16x8*)&sBL[d] = *(const bf16x8*)(pl + bsrc);
      } else {
        size_t bsrc = ((size_t)(b*Nn + Lrow)) * Hh + (k0 - 256) + cc*8;
        *(bf16x8*)&sBH[d] = *(const bf16x8*)(eh + bsrc);
        *(bf16x8*)&sBL[d] = *(const bf16x8*)(el + bsrc);
      }
    }
    __syncthreads();
#pragma unroll
    for (int kk = 0; kk < 64; kk += 32) {
      bf16x8 ahi[4], alo[4], bhi[2], blo[2];
#pragma unroll
      for (int fm = 0; fm < 4; ++fm) {
        int d = SW(wo*64 + fm*16 + l15, (kk>>3) + lk);
        ahi[fm] = *(const bf16x8*)&sAH[d];
        alo[fm] = *(const bf16x8*)&sAL[d];
      }
#pragma unroll
      for (int fn = 0; fn < 2; ++fn) {
        int d = SW(wg*32 + fn*16 + l15, (kk>>3) + lk);
        bhi[fn] = *(const bf16x8*)&sBH[d];
        blo[fn] = *(const bf16x8*)&sBL[d];
      }
#pragma unroll
      for (int fm = 0; fm < 4; ++fm)
#pragma unroll
        for (int fn = 0; fn < 2; ++fn) {
          acc[fm][fn] = MFMA(ahi[fm], bhi[fn], acc[fm][fn]);
          acc[fm][fn] = MFMA(ahi[fm], blo[fn], acc[fm][fn]);
          acc[fm][fn] = MFMA(alo[fm], bhi[fn], acc[fm][fn]);
        }
    }
    __syncthreads();
  }
#pragma unroll
  for (int fm = 0; fm < 4; ++fm) {
    int o = o0 + wo*64 + fm*16 + lk*4;
    float4 qv = *(const float4*)(ws + WS_QG + b*Hh + o);
    float q4[4] = {qv.x, qv.y, qv.z, qv.w};
#pragma unroll
    for (int fn = 0; fn < 2; ++fn) {
      int g = g0 + wg*32 + fn*16 + l15;
      u16x4 vh, vl;
#pragma unroll
      for (int j = 0; j < 4; ++j) {
        unsigned short hi, lo;
        split1(acc[fm][fn][j] + q4[j], hi, lo);
        vh[j] = hi; vl[j] = lo;
      }
      size_t idx = ((size_t)(b*GP + g)) * Hh + o;
      *(u16x4*)(fh + idx) = vh;
      *(u16x4*)(fl + idx) = vl;
    }
  }
}

// ---------------- score GEMM + fp16 p + rowsum atomics ----------------
// grid(nt=8, gt=4, b=64), block(512)=8 waves (2 wn x 4 wg), wave 64n x 32g, K=256
__global__ __launch_bounds__(512, 2) void k_score(const float* __restrict__ dists,
                                                  const int* __restrict__ last_node,
                                                  float* __restrict__ ws) {
  __shared__ __align__(16) unsigned short sEH[128*64], sEL[128*64],
                                          sFH[128*64], sFL[128*64];
  __shared__ int lL[128];
  int nt = blockIdx.x, gt = blockIdx.y, b = blockIdx.z;
  int t = threadIdx.x, w = t >> 6, lane = t & 63;
  int wn = w >> 2, wg = w & 3, l15 = lane & 15, lk = lane >> 4;
  const unsigned short* eh = (const unsigned short*)(ws + WS_EH);
  const unsigned short* el = (const unsigned short*)(ws + WS_EL);
  const unsigned short* fh = (const unsigned short*)(ws + WS_FH);
  const unsigned short* fl = (const unsigned short*)(ws + WS_FL);
  const unsigned short* bmp = (const unsigned short*)(ws + WS_BM);
  unsigned short* po = (unsigned short*)(ws + WS_PO);
  float* rs = ws + WS_RS;
  int n0 = nt*128, g0 = gt*128;
  if (t < 128) lL[t] = last_node[b*Gg + ((g0 + t) < Gg ? (g0 + t) : Gg-1)];
  __syncthreads();
  f32x4 acc[4][2] = {};
  int srow = t >> 2, scb = t & 3;
  int nr = n0 + srow; if (nr > Nn-1) nr = Nn-1;
  size_t ebase = ((size_t)(b*Nn + nr)) * Hh;
  size_t fbase = ((size_t)(b*GP + g0 + srow)) * Hh;
  for (int st = 0; st < 4; ++st) {
    int k0 = st * 64;
#pragma unroll
    for (int i = 0; i < 2; ++i) {
      int cc = scb + i*4;
      int d = SW(srow, cc);
      *(bf16x8*)&sEH[d] = *(const bf16x8*)(eh + ebase + k0 + cc*8);
      *(bf16x8*)&sEL[d] = *(const bf16x8*)(el + ebase + k0 + cc*8);
      *(bf16x8*)&sFH[d] = *(const bf16x8*)(fh + fbase + k0 + cc*8);
      *(bf16x8*)&sFL[d] = *(const bf16x8*)(fl + fbase + k0 + cc*8);
    }
    __syncthreads();
#pragma unroll
    for (int kk = 0; kk < 64; kk += 32) {
      bf16x8 ahi[4], alo[4], bhi[2], blo[2];
#pragma unroll
      for (int fm = 0; fm < 4; ++fm) {
        int d = SW(wn*64 + fm*16 + l15, (kk>>3) + lk);
        ahi[fm] = *(const bf16x8*)&sEH[d];
        alo[fm] = *(const bf16x8*)&sEL[d];
      }
#pragma unroll
      for (int fn = 0; fn < 2; ++fn) {
        int d = SW(wg*32 + fn*16 + l15, (kk>>3) + lk);
        bhi[fn] = *(const bf16x8*)&sFH[d];
        blo[fn] = *(const bf16x8*)&sFL[d];
      }
#pragma unroll
      for (int fm = 0; fm < 4; ++fm)
#pragma unroll
        for (int fn = 0; fn < 2; ++fn) {
          acc[fm][fn] = MFMA(ahi[fm], bhi[fn], acc[fm][fn]);
          acc[fm][fn] = MFMA(ahi[fm], blo[fn], acc[fm][fn]);
          acc[fm][fn] = MFMA(alo[fm], bhi[fn], acc[fm][fn]);
        }
    }
    __syncthreads();
  }
  const float c2 = 0.70710678118654752f;
  float rsum[2] = {0.f, 0.f};
#pragma unroll
  for (int fn = 0; fn < 2; ++fn) {
    int gl = wg*32 + fn*16 + l15;
    int g = g0 + gl;
    if (g < Gg) {
      int L = lL[gl];
      const float* drow = dists + ((size_t)(b*Nn + L)) * Nn;
      const unsigned short* bmr = bmp + ((size_t)(b*GP + g)) * 64;
      unsigned short* prow = po + (size_t)(b*GP + g) * 1000;
#pragma unroll
      for (int fm = 0; fm < 4; ++fm) {
        int n = n0 + wn*64 + fm*16 + lk*4;
        if (n < Nn) {
          float4 d4 = *(const float4*)(drow + n);
          unsigned cb = bmr[n >> 4];
          int bo = n & 15;
          float dd[4] = {d4.x, d4.y, d4.z, d4.w};
          unsigned short h4[4];
#pragma unroll
          for (int j = 0; j < 4; ++j) {
            float sc = acc[fm][fn][j] * 0.0625f - dd[j] * c2;
            float p = ((cb >> (bo + j)) & 1) ? 0.f : __expf(tanh10(sc) - 10.0f);
            rsum[fn] += p;
            h4[j] = __half_as_ushort(__float2half(p));
          }
          uint2 u = { (unsigned)h4[0] | ((unsigned)h4[1] << 16),
                      (unsigned)h4[2] | ((unsigned)h4[3] << 16) };
          *(uint2*)(prow + n) = u;
        }
      }
    }
  }
#pragma unroll
  for (int fn = 0; fn < 2; ++fn) {
    rsum[fn] += __shfl_xor(rsum[fn], 16);
    rsum[fn] += __shfl_xor(rsum[fn], 32);
    int g = g0 + wg*32 + fn*16 + l15;
    if (lk == 0 && g < Gg) atomicAdd(rs + b*GP + g, rsum[fn]);
  }
}

// ---------------- normalize: out[g][n] = fp16 p * (1/rs): grid(31250) ---------
__global__ __launch_bounds__(256) void k_norm(const float* __restrict__ ws,
                                              float* __restrict__ out) {
  int idx = blockIdx.x * 256 + threadIdx.x;   // float4 index, < 8,000,000
  int bg = idx / 250;                         // b*Gg + g
  int n = (idx - bg * 250) * 4;
  int b = bg / Gg, g = bg - b * Gg;
  const unsigned short* po = (const unsigned short*)(ws + WS_PO);
  float inv = 1.0f / ws[WS_RS + b*GP + g];
  uint2 u = *(const uint2*)(po + (size_t)(b*GP + g) * 1000 + n);
  float4 o4;
  o4.x = __half2float(__ushort_as_half((unsigned short)(u.x & 0xFFFF))) * inv;
  o4.y = __half2float(__ushort_as_half((unsigned short)(u.x >> 16))) * inv;
  o4.z = __half2float(__ushort_as_half((unsigned short)(u.y & 0xFFFF))) * inv;
  o4.w = __half2float(__ushort_as_half((unsigned short)(u.y >> 16))) * inv;
  *(float4*)(out + (size_t)bg * Nn + n) = o4;
}

extern "C" void kernel_launch(void* const* d_in, const int* in_sizes, int n_in,
                              void* d_out, int out_size, void* d_ws, size_t ws_size,
                              hipStream_t stream) {
  const float* emb       = (const float*)d_in[0];
  const float* dists     = (const float*)d_in[1];
  const int*   last_node = (const int*)d_in[2];
  const float* gm        = (const float*)d_in[3];
  const float* Wg        = (const float*)d_in[4];
  const float* Wf        = (const float*)d_in[5];
  const float* Wl        = (const float*)d_in[6];
  const float* Wv        = (const float*)d_in[7];
  float* out = (float*)d_out;
  float* ws  = (float*)d_ws;

  hipLaunchKernelGGL(k_zero,   dim3(192),       dim3(256), 0, stream, ws);
  hipLaunchKernelGGL(k_prep,   dim3(16,4,Bb),   dim3(256), 0, stream, emb, ws);
  hipLaunchKernelGGL(k_qgraph, dim3(Bb),        dim3(256), 0, stream, Wg, ws);
  hipLaunchKernelGGL(k_wcat,   dim3(256),       dim3(256), 0, stream, Wf, Wl, Wv, ws);
  hipLaunchKernelGGL(k_bm,     dim3(Bb*GP/4),   dim3(256), 0, stream, gm, ws);
  hipLaunchKernelGGL(k_pool,   dim3(2,4,Bb),    dim3(512), 0, stream, ws);
  hipLaunchKernelGGL(k_finalq, dim3(2,4,Bb),    dim3(512), 0, stream, last_node, ws);
  hipLaunchKernelGGL(k_score,  dim3(8,4,Bb),    dim3(512), 0, stream, dists, last_node, ws);
  hipLaunchKernelGGL(k_norm,   dim3(31250),     dim3(256), 0, stream, ws, out);
}

// Round 8
// 372.498 us; speedup vs baseline: 1.8089x; 1.1195x over previous
//
#include <hip/hip_runtime.h>
#include <hip/hip_fp16.h>
#include <math.h>

#define Bb 64
#define Nn 1000
#define Gg 500
#define Hh 256
#define GP 512
#define NP 1024

// float offsets into d_ws (total 42,762,240 floats = 171 MB)
#define WS_MP   0u           // [B][H] fp32 column sums (zeroed each launch)
#define WS_QG   16384u       // [B][H] fp32 q_graph
#define WS_BM   32768u       // u16 [B][GP][64] visited bitmask
#define WS_WCH  1081344u     // u16 [256][512] Wcat hi
#define WS_WCL  1146880u     // u16 [256][512] Wcat lo
#define WS_EH   1212416u     // u16 [B][N][H] emb hi
#define WS_EL   9404416u     // u16 [B][N][H] emb lo
#define WS_TH   17596416u    // u16 [B][H][NP] embT hi (dead after k_pool)
#define WS_PH   25985024u    // u16 [B][GP][H] pooled hi (dead after k_finalq)
#define WS_PL2  30179328u    // u16 [B][GP][H] pooled lo (dead after k_finalq)
#define WS_FH   17596416u    // u16 [B][GP][H] fq hi (overlays embT TH)
#define WS_FL   21790720u    // u16 [B][GP][H] fq lo (overlays TH 2nd half)
#define WS_PO   25985024u    // u16 [B][500][1024] unnorm p (overlays PH+PL2+...)
#define WS_RS   42369024u    // [B][GP] fp32 row sums (exclusive, zeroed)

typedef __attribute__((ext_vector_type(8))) short bf16x8;
typedef __attribute__((ext_vector_type(8))) short short8;
typedef __attribute__((ext_vector_type(4))) float f32x4;
typedef __attribute__((ext_vector_type(4))) unsigned short u16x4;

#define MFMA(a,b,c) __builtin_amdgcn_mfma_f32_16x16x32_bf16(a,b,c,0,0,0)
// swizzled LDS offset (shorts): 64-short rows, 8 chunks of 8 bf16 (16B)
#define SW(row, chunk) (((row) << 6) + ((((chunk) ^ ((row) & 7))) << 3))

// round-to-nearest bf16 split: hi = RN(v), lo = RN(v - hi)
__device__ __forceinline__ unsigned short bf16rn(float v) {
  unsigned bits = __float_as_uint(v);
  unsigned r = bits + 0x7FFFu + ((bits >> 16) & 1u);
  return (unsigned short)(r >> 16);
}
__device__ __forceinline__ void split1(float v, unsigned short& hi, unsigned short& lo) {
  hi = bf16rn(v);
  float hf = __uint_as_float(((unsigned)hi) << 16);
  lo = bf16rn(v - hf);
}

// ---------------- zero MP + RS: grid(192), block(256) ----------------
__global__ __launch_bounds__(256) void k_zero(float* __restrict__ ws) {
  int bid = blockIdx.x, t = threadIdx.x;
  if (bid < 64) ws[WS_MP + bid * 256 + t] = 0.f;
  else          ws[WS_RS + (bid - 64) * 256 + t] = 0.f;
}

// ---------------- prep: emb -> eh/el + th + column sums ----------------
// grid(nt=16, ht=4, b=64), block(256)
__global__ __launch_bounds__(256) void k_prep(const float* __restrict__ emb,
                                              float* __restrict__ ws) {
  __shared__ float tile[64][65];
  __shared__ float csumL[256];
  int nt = blockIdx.x, ht = blockIdx.y, b = blockIdx.z;
  int t = threadIdx.x, c = t & 63, w = t >> 6;
  int n0 = nt * 64, h0 = ht * 64;
  unsigned short* eh = (unsigned short*)(ws + WS_EH);
  unsigned short* el = (unsigned short*)(ws + WS_EL);
  unsigned short* th = (unsigned short*)(ws + WS_TH);
  float csum = 0.f;
#pragma unroll
  for (int rr = 0; rr < 16; ++rr) {
    int r = w * 16 + rr;
    int n = n0 + r;
    float v = 0.f;
    if (n < Nn) {
      size_t idx = ((size_t)(b * Nn + n)) * Hh + h0 + c;
      v = emb[idx];
      unsigned short hi, lo;
      split1(v, hi, lo);
      eh[idx] = hi; el[idx] = lo;
    }
    tile[r][c] = v;
    csum += v;
  }
  __syncthreads();
  {
    int h_l = t >> 2, nseg = t & 3;
    short8 h8a, h8b;
#pragma unroll
    for (int i = 0; i < 16; ++i) {
      float v = tile[nseg * 16 + i][h_l];
      unsigned short hi = bf16rn(v);
      if (i < 8) h8a[i] = (short)hi;
      else       h8b[i-8] = (short)hi;
    }
    size_t base = ((size_t)(b * Hh + h0 + h_l)) * NP + n0 + nseg * 16;
    *(short8*)(th + base) = h8a; *(short8*)(th + base + 8) = h8b;
  }
  __syncthreads();
  csumL[t] = csum;
  __syncthreads();
  if (t < 64) {
    float s = csumL[t] + csumL[t+64] + csumL[t+128] + csumL[t+192];
    atomicAdd(ws + WS_MP + b * Hh + h0 + t, s);
  }
}

// ---------------- q_graph: grid(B), block(256) ----------------
__global__ __launch_bounds__(256) void k_qgraph(const float* __restrict__ Wg,
                                                float* __restrict__ ws) {
  __shared__ float mean[Hh];
  int b = blockIdx.x, t = threadIdx.x;
  mean[t] = ws[WS_MP + b*Hh + t] * (1.0f/Nn);
  __syncthreads();
  const float4* wrow = (const float4*)(Wg + (size_t)t * Hh);
  float acc = 0.f;
#pragma unroll
  for (int h4 = 0; h4 < Hh/4; ++h4) {
    float4 w = wrow[h4];
    acc += mean[h4*4]*w.x + mean[h4*4+1]*w.y + mean[h4*4+2]*w.z + mean[h4*4+3]*w.w;
  }
  ws[WS_QG + b*Hh + t] = acc;
}

// ---------------- Wcat bf16 hi/lo: grid(256), block(256) ----------------
__global__ __launch_bounds__(256) void k_wcat(const float* __restrict__ Wf,
                                              const float* __restrict__ Wl,
                                              const float* __restrict__ Wv,
                                              float* __restrict__ ws) {
  int o = blockIdx.x, k = threadIdx.x;
  unsigned short* wh = (unsigned short*)(ws + WS_WCH);
  unsigned short* wl = (unsigned short*)(ws + WS_WCL);
  unsigned short hi, lo;
  float v0 = Wv[o*Hh + k];
  split1(v0, hi, lo);
  wh[o*512 + k] = hi; wl[o*512 + k] = lo;
  float v1 = Wl[o*Hh + k] + Wf[o*Hh + k];
  split1(v1, hi, lo);
  wh[o*512 + 256 + k] = hi; wl[o*512 + 256 + k] = lo;
}

// ---------------- bitmask: gm -> 1 bit per (b,g,n): grid(B*GP/4), block(256) ----
__global__ __launch_bounds__(256) void k_bm(const float* __restrict__ gm,
                                            float* __restrict__ ws) {
  int w = threadIdx.x >> 6, l = threadIdx.x & 63;
  int row = blockIdx.x * 4 + w;          // b*GP + g
  int b = row >> 9, g = row & 511;
  unsigned long long* dst = (unsigned long long*)((unsigned short*)(ws + WS_BM) + (size_t)row * 64);
  if (g < Gg) {
    const float* src = gm + ((size_t)b * Gg + g) * Nn;
#pragma unroll
    for (int i = 0; i < 16; ++i) {
      int n = i * 64 + l;
      bool bit = (n < Nn) ? (src[n] < -1e30f) : false;
      unsigned long long m = __ballot(bit);
      if (l == i) dst[i] = m;
    }
  } else {
    if (l < 16) dst[l] = 0ull;
  }
}

// ---------------- pool GEMM: pooled[g][h] = (1/N) mask @ emb_hi ----------------
// grid(ht=2, gt=4, b=64), block(512)=8 waves (2 wh x 4 wg), wave 64h x 32g, BK=64
__global__ __launch_bounds__(512, 2) void k_pool(float* __restrict__ ws) {
  __shared__ __align__(16) unsigned short sTH[128*64];
  int ht = blockIdx.x, gt = blockIdx.y, b = blockIdx.z;
  int t = threadIdx.x, w = t >> 6, lane = t & 63;
  int wh = w >> 2, wg = w & 3, l15 = lane & 15, lk = lane >> 4;
  const unsigned short* th = (const unsigned short*)(ws + WS_TH);
  const unsigned short* bmp = (const unsigned short*)(ws + WS_BM);
  unsigned short* ph = (unsigned short*)(ws + WS_PH);
  unsigned short* pl = (unsigned short*)(ws + WS_PL2);
  int h0 = ht*128, g0 = gt*128;
  f32x4 acc[4][2] = {};
  const unsigned short* brow[2];
#pragma unroll
  for (int fn = 0; fn < 2; ++fn)
    brow[fn] = bmp + ((size_t)(b*GP + g0 + wg*32 + fn*16 + l15)) * 64;
  int bitoff = (lk & 1) * 8;
  int srow = t >> 2, scb = t & 3;
  size_t sbase = ((size_t)(b*Hh + h0 + srow)) * NP;
  for (int st = 0; st < 16; ++st) {
    int k0 = st * 64;
#pragma unroll
    for (int i = 0; i < 2; ++i) {
      int cc = scb + i*4;
      int d = SW(srow, cc);
      *(bf16x8*)&sTH[d] = *(const bf16x8*)(th + sbase + k0 + cc*8);
    }
    __syncthreads();
#pragma unroll
    for (int kk = 0; kk < 64; kk += 32) {
      bf16x8 ah[4], bmf[2];
#pragma unroll
      for (int fm = 0; fm < 4; ++fm) {
        int ar = wh*64 + fm*16 + l15;
        int d = SW(ar, (kk>>3) + lk);
        ah[fm] = *(const bf16x8*)&sTH[d];
      }
#pragma unroll
      for (int fn = 0; fn < 2; ++fn) {
        unsigned c = brow[fn][((k0 + kk) >> 4) + (lk >> 1)];
#pragma unroll
        for (int i = 0; i < 8; ++i)
          bmf[fn][i] = ((c >> (bitoff + i)) & 1) ? (short)0x3F80 : (short)0;
      }
#pragma unroll
      for (int fm = 0; fm < 4; ++fm)
#pragma unroll
        for (int fn = 0; fn < 2; ++fn)
          acc[fm][fn] = MFMA(ah[fm], bmf[fn], acc[fm][fn]);
    }
    __syncthreads();
  }
#pragma unroll
  for (int fm = 0; fm < 4; ++fm)
#pragma unroll
    for (int fn = 0; fn < 2; ++fn) {
      int h = h0 + wh*64 + fm*16 + lk*4;
      int g = g0 + wg*32 + fn*16 + l15;
      u16x4 vh, vl;
#pragma unroll
      for (int j = 0; j < 4; ++j) {
        unsigned short hi, lo;
        split1(acc[fm][fn][j] * (1.0f/Nn), hi, lo);
        vh[j] = hi; vl[j] = lo;
      }
      size_t idx = ((size_t)(b*GP + g)) * Hh + h;
      *(u16x4*)(ph + idx) = vh;
      *(u16x4*)(pl + idx) = vl;
    }
}

// ---------------- finalq GEMM: fq[g][o] = Wcat@[pooled|lastE]^T + qg ----------
// grid(ot=2, gt=4, b=64), block(512)=8 waves (2 wo x 4 wg), wave 64o x 32g, K=512
__global__ __launch_bounds__(512, 2) void k_finalq(const int* __restrict__ last_node,
                                                   float* __restrict__ ws) {
  __shared__ __align__(16) unsigned short sAH[128*64], sAL[128*64],
                                          sBH[128*64], sBL[128*64];
  __shared__ int lL[128];
  int ot = blockIdx.x, gt = blockIdx.y, b = blockIdx.z;
  int t = threadIdx.x, w = t >> 6, lane = t & 63;
  int wo = w >> 2, wg = w & 3, l15 = lane & 15, lk = lane >> 4;
  const unsigned short* wch = (const unsigned short*)(ws + WS_WCH);
  const unsigned short* wcl = (const unsigned short*)(ws + WS_WCL);
  const unsigned short* ph = (const unsigned short*)(ws + WS_PH);
  const unsigned short* pl = (const unsigned short*)(ws + WS_PL2);
  const unsigned short* eh = (const unsigned short*)(ws + WS_EH);
  const unsigned short* el = (const unsigned short*)(ws + WS_EL);
  unsigned short* fh = (unsigned short*)(ws + WS_FH);
  unsigned short* fl = (unsigned short*)(ws + WS_FL);
  int o0 = ot*128, g0 = gt*128;
  if (t < 128) lL[t] = last_node[b*Gg + ((g0 + t) < Gg ? (g0 + t) : Gg-1)];
  __syncthreads();
  f32x4 acc[4][2] = {};
  int srow = t >> 2, scb = t & 3;
  size_t abase = ((size_t)(o0 + srow)) * 512;
  int Lrow = lL[srow];
  for (int st = 0; st < 8; ++st) {
    int k0 = st * 64;
#pragma unroll
    for (int i = 0; i < 2; ++i) {
      int cc = scb + i*4;
      int d = SW(srow, cc);
      *(bf16x8*)&sAH[d] = *(const bf16x8*)(wch + abase + k0 + cc*8);
      *(bf16x8*)&sAL[d] = *(const bf16x8*)(wcl + abase + k0 + cc*8);
      if (k0 < 256) {
        size_t bsrc = ((size_t)(b*GP + g0 + srow)) * Hh + k0 + cc*8;
        *(bf16x8*)&sBH[d] = *(const bf16x8*)(ph + bsrc);
        *(bf16x8*)&sBL[d] = *(const bf16x8*)(pl + bsrc);
      } else {
        size_t bsrc = ((size_t)(b*Nn + Lrow)) * Hh + (k0 - 256) + cc*8;
        *(bf16x8*)&sBH[d] = *(const bf16x8*)(eh + bsrc);
        *(bf16x8*)&sBL[d] = *(const bf16x8*)(el + bsrc);
      }
    }
    __syncthreads();
#pragma unroll
    for (int kk = 0; kk < 64; kk += 32) {
      bf16x8 ahi[4], alo[4], bhi[2], blo[2];
#pragma unroll
      for (int fm = 0; fm < 4; ++fm) {
        int d = SW(wo*64 + fm*16 + l15, (kk>>3) + lk);
        ahi[fm] = *(const bf16x8*)&sAH[d];
        alo[fm] = *(const bf16x8*)&sAL[d];
      }
#pragma unroll
      for (int fn = 0; fn < 2; ++fn) {
        int d = SW(wg*32 + fn*16 + l15, (kk>>3) + lk);
        bhi[fn] = *(const bf16x8*)&sBH[d];
        blo[fn] = *(const bf16x8*)&sBL[d];
      }
#pragma unroll
      for (int fm = 0; fm < 4; ++fm)
#pragma unroll
        for (int fn = 0; fn < 2; ++fn) {
          acc[fm][fn] = MFMA(ahi[fm], bhi[fn], acc[fm][fn]);
          acc[fm][fn] = MFMA(ahi[fm], blo[fn], acc[fm][fn]);
          acc[fm][fn] = MFMA(alo[fm], bhi[fn], acc[fm][fn]);
        }
    }
    __syncthreads();
  }
#pragma unroll
  for (int fm = 0; fm < 4; ++fm) {
    int o = o0 + wo*64 + fm*16 + lk*4;
    float4 qv = *(const float4*)(ws + WS_QG + b*Hh + o);
    float q4[4] = {qv.x, qv.y, qv.z, qv.w};
#pragma unroll
    for (int fn = 0; fn < 2; ++fn) {
      int g = g0 + wg*32 + fn*16 + l15;
      u16x4 vh, vl;
#pragma unroll
      for (int j = 0; j < 4; ++j) {
        unsigned short hi, lo;
        split1(acc[fm][fn][j] + q4[j], hi, lo);
        vh[j] = hi; vl[j] = lo;
      }
      size_t idx = ((size_t)(b*GP + g)) * Hh + o;
      *(u16x4*)(fh + idx) = vh;
      *(u16x4*)(fl + idx) = vl;
    }
  }
}

// ---------------- score GEMM + fp16 p + rowsum atomics ----------------
// grid(nt=8, gt=4, b=64), block(512)=8 waves (2 wn x 4 wg), wave 64n x 32g, K=256
__global__ __launch_bounds__(512, 2) void k_score(const float* __restrict__ dists,
                                                  const int* __restrict__ last_node,
                                                  float* __restrict__ ws) {
  __shared__ __align__(16) unsigned short sEH[128*64], sEL[128*64],
                                          sFH[128*64], sFL[128*64];
  __shared__ int lL[128];
  int nt = blockIdx.x, gt = blockIdx.y, b = blockIdx.z;
  int t = threadIdx.x, w = t >> 6, lane = t & 63;
  int wn = w >> 2, wg = w & 3, l15 = lane & 15, lk = lane >> 4;
  const unsigned short* eh = (const unsigned short*)(ws + WS_EH);
  const unsigned short* el = (const unsigned short*)(ws + WS_EL);
  const unsigned short* fh = (const unsigned short*)(ws + WS_FH);
  const unsigned short* fl = (const unsigned short*)(ws + WS_FL);
  const unsigned short* bmp = (const unsigned short*)(ws + WS_BM);
  unsigned short* po = (unsigned short*)(ws + WS_PO);
  float* rs = ws + WS_RS;
  int n0 = nt*128, g0 = gt*128;
  if (t < 128) lL[t] = last_node[b*Gg + ((g0 + t) < Gg ? (g0 + t) : Gg-1)];
  __syncthreads();
  f32x4 acc[4][2] = {};
  int srow = t >> 2, scb = t & 3;
  int nr = n0 + srow; if (nr > Nn-1) nr = Nn-1;
  size_t ebase = ((size_t)(b*Nn + nr)) * Hh;
  size_t fbase = ((size_t)(b*GP + g0 + srow)) * Hh;
  for (int st = 0; st < 4; ++st) {
    int k0 = st * 64;
#pragma unroll
    for (int i = 0; i < 2; ++i) {
      int cc = scb + i*4;
      int d = SW(srow, cc);
      *(bf16x8*)&sEH[d] = *(const bf16x8*)(eh + ebase + k0 + cc*8);
      *(bf16x8*)&sEL[d] = *(const bf16x8*)(el + ebase + k0 + cc*8);
      *(bf16x8*)&sFH[d] = *(const bf16x8*)(fh + fbase + k0 + cc*8);
      *(bf16x8*)&sFL[d] = *(const bf16x8*)(fl + fbase + k0 + cc*8);
    }
    __syncthreads();
#pragma unroll
    for (int kk = 0; kk < 64; kk += 32) {
      bf16x8 ahi[4], alo[4], bhi[2], blo[2];
#pragma unroll
      for (int fm = 0; fm < 4; ++fm) {
        int d = SW(wn*64 + fm*16 + l15, (kk>>3) + lk);
        ahi[fm] = *(const bf16x8*)&sEH[d];
        alo[fm] = *(const bf16x8*)&sEL[d];
      }
#pragma unroll
      for (int fn = 0; fn < 2; ++fn) {
        int d = SW(wg*32 + fn*16 + l15, (kk>>3) + lk);
        bhi[fn] = *(const bf16x8*)&sFH[d];
        blo[fn] = *(const bf16x8*)&sFL[d];
      }
#pragma unroll
      for (int fm = 0; fm < 4; ++fm)
#pragma unroll
        for (int fn = 0; fn < 2; ++fn) {
          acc[fm][fn] = MFMA(ahi[fm], bhi[fn], acc[fm][fn]);
          acc[fm][fn] = MFMA(ahi[fm], blo[fn], acc[fm][fn]);
          acc[fm][fn] = MFMA(alo[fm], bhi[fn], acc[fm][fn]);
        }
    }
    __syncthreads();
  }
  const float c2 = 0.70710678118654752f;
  float rsum[2] = {0.f, 0.f};
#pragma unroll
  for (int fn = 0; fn < 2; ++fn) {
    int gl = wg*32 + fn*16 + l15;
    int g = g0 + gl;
    if (g < Gg) {
      int L = lL[gl];
      const float* drow = dists + ((size_t)(b*Nn + L)) * Nn;
      const unsigned short* bmr = bmp + ((size_t)(b*GP + g)) * 64;
      unsigned short* prow = po + ((size_t)(b*Gg + g)) * 1024;
#pragma unroll
      for (int fm = 0; fm < 4; ++fm) {
        int n = n0 + wn*64 + fm*16 + lk*4;
        if (n < Nn) {
          float4 d4 = *(const float4*)(drow + n);
          unsigned cb = bmr[n >> 4];
          int bo = n & 15;
          float dd[4] = {d4.x, d4.y, d4.z, d4.w};
          unsigned short h4[4];
#pragma unroll
          for (int j = 0; j < 4; ++j) {
            // p = exp(10*tanh(s) - 10), exp2-domain, rcp-approx division
            float s = fmaf(acc[fm][fn][j], 0.0625f, -dd[j] * c2);
            float e = __expf(-2.0f * fabsf(s));
            float r = __builtin_amdgcn_rcpf(1.0f + e);
            float m = fmaf(-20.0f, e * r, 10.0f);   // = 10*tanh(|s|)
            float parg = copysignf(m, s) - 10.0f;
            float p = ((cb >> (bo + j)) & 1) ? 0.f : __expf(parg);
            rsum[fn] += p;
            h4[j] = __half_as_ushort(__float2half(p));
          }
          uint2 u = { (unsigned)h4[0] | ((unsigned)h4[1] << 16),
                      (unsigned)h4[2] | ((unsigned)h4[3] << 16) };
          *(uint2*)(prow + n) = u;
        }
      }
    }
  }
#pragma unroll
  for (int fn = 0; fn < 2; ++fn) {
    rsum[fn] += __shfl_xor(rsum[fn], 16);
    rsum[fn] += __shfl_xor(rsum[fn], 32);
    int g = g0 + wg*32 + fn*16 + l15;
    if (lk == 0 && g < Gg) atomicAdd(rs + b*GP + g, rsum[fn]);
  }
}

// ---------------- normalize: out[g][n] = fp16 p * (1/rs): grid(31250) ---------
__global__ __launch_bounds__(256) void k_norm(const float* __restrict__ ws,
                                              float* __restrict__ out) {
  int idx = blockIdx.x * 256 + threadIdx.x;   // float4 index, < 8,000,000
  int bg = idx / 250;                         // b*Gg + g
  int n = (idx - bg * 250) * 4;
  int b = bg / Gg, g = bg - b * Gg;
  const unsigned short* po = (const unsigned short*)(ws + WS_PO);
  float inv = 1.0f / ws[WS_RS + b*GP + g];
  uint2 u = *(const uint2*)(po + (size_t)bg * 1024 + n);
  float4 o4;
  o4.x = __half2float(__ushort_as_half((unsigned short)(u.x & 0xFFFF))) * inv;
  o4.y = __half2float(__ushort_as_half((unsigned short)(u.x >> 16))) * inv;
  o4.z = __half2float(__ushort_as_half((unsigned short)(u.y & 0xFFFF))) * inv;
  o4.w = __half2float(__ushort_as_half((unsigned short)(u.y >> 16))) * inv;
  *(float4*)(out + (size_t)bg * Nn + n) = o4;
}

extern "C" void kernel_launch(void* const* d_in, const int* in_sizes, int n_in,
                              void* d_out, int out_size, void* d_ws, size_t ws_size,
                              hipStream_t stream) {
  const float* emb       = (const float*)d_in[0];
  const float* dists     = (const float*)d_in[1];
  const int*   last_node = (const int*)d_in[2];
  const float* gm        = (const float*)d_in[3];
  const float* Wg        = (const float*)d_in[4];
  const float* Wf        = (const float*)d_in[5];
  const float* Wl        = (const float*)d_in[6];
  const float* Wv        = (const float*)d_in[7];
  float* out = (float*)d_out;
  float* ws  = (float*)d_ws;

  hipLaunchKernelGGL(k_zero,   dim3(192),       dim3(256), 0, stream, ws);
  hipLaunchKernelGGL(k_prep,   dim3(16,4,Bb),   dim3(256), 0, stream, emb, ws);
  hipLaunchKernelGGL(k_qgraph, dim3(Bb),        dim3(256), 0, stream, Wg, ws);
  hipLaunchKernelGGL(k_wcat,   dim3(256),       dim3(256), 0, stream, Wf, Wl, Wv, ws);
  hipLaunchKernelGGL(k_bm,     dim3(Bb*GP/4),   dim3(256), 0, stream, gm, ws);
  hipLaunchKernelGGL(k_pool,   dim3(2,4,Bb),    dim3(512), 0, stream, ws);
  hipLaunchKernelGGL(k_finalq, dim3(2,4,Bb),    dim3(512), 0, stream, last_node, ws);
  hipLaunchKernelGGL(k_score,  dim3(8,4,Bb),    dim3(512), 0, stream, dists, last_node, ws);
  hipLaunchKernelGGL(k_norm,   dim3(31250),     dim3(256), 0, stream, ws, out);
}